// Round 1
// baseline (216.084 us; speedup 1.0000x reference)
//
#include <hip/hip_runtime.h>

#define B_ 4
#define S_ 2048
#define E_ 1024

typedef __attribute__((ext_vector_type(8))) short short8;
typedef __attribute__((ext_vector_type(4))) float f32x4;

__device__ __forceinline__ unsigned short f2bu(float f) {
  unsigned u = __builtin_bit_cast(unsigned, f);
  u = (u + 0x7FFFu + ((u >> 16) & 1u)) >> 16;
  return (unsigned short)u;
}

__device__ __forceinline__ void gload_lds16(const void* g, void* l) {
  __builtin_amdgcn_global_load_lds(
      (const __attribute__((address_space(1))) void*)g,
      (__attribute__((address_space(3))) void*)l, 16, 0, 0);
}

// ---------------- fp32 -> bf16 convert ----------------
__global__ __launch_bounds__(256) void cvt_f32_bf16(
    const float* __restrict__ in, unsigned short* __restrict__ out, int n) {
  int i = blockIdx.x * 256 + threadIdx.x;
  if (i * 4 >= n) return;
  float4 v = ((const float4*)in)[i];
  ushort4 o;
  o.x = f2bu(v.x); o.y = f2bu(v.y); o.z = f2bu(v.z); o.w = f2bu(v.w);
  ((ushort4*)out)[i] = o;
}

// ---------------- generic B^T GEMM, m97 structure ----------------
// C[m][n] = scale * sum_k A[m][k]*B[n][k] + bias[n]
// A: (M x K) bf16 row-major (lda), B: (N x K) bf16 row-major (ldb)
// OUT_BF16: C is bf16 else fp32.  STORE_TRANS: C[n*ldc + m] (packed 4-row stores).
// CAUSAL_SKIP: skip tiles bn>bm (square tile grid). K_BOUND: Keff=min(K,(bm+1)*128).
template<bool OUT_BF16, bool BIAS, bool CAUSAL_SKIP, bool K_BOUND, bool STORE_TRANS>
__global__ __launch_bounds__(256, 2) void gemm_bt(
    const unsigned short* __restrict__ A, long sAz, int lda,
    const unsigned short* __restrict__ B, long sBz, int ldb,
    const float* __restrict__ bias,
    void* __restrict__ C, long sCz, int ldc,
    int M, int N, int K, float scale) {
  constexpr int BM = 128, BN = 128, BK = 64;
  __shared__ unsigned short lA[BM * BK];
  __shared__ unsigned short lB[BN * BK];
  int bm = blockIdx.y, bn = blockIdx.x, bz = blockIdx.z;
  if (CAUSAL_SKIP && bn > bm) return;
  const unsigned short* Ab = A + (long)bz * sAz + (long)bm * BM * lda;
  const unsigned short* Bb = B + (long)bz * sBz + (long)bn * BN * ldb;
  int Keff = K_BOUND ? min(K, (bm + 1) * BM) : K;

  int tid = threadIdx.x;
  int l = tid & 63, w = tid >> 6;
  int wm = w >> 1, wn = w & 1;  // wave computes 64x64 at (wm*64, wn*64)

  // staging: per K-step each tile is 16KB = 16 chunks of 1KB (64 lanes x 16B)
  int srow = l >> 3;            // row within 8-row chunk
  int schunk = (l & 7) * 8;     // element offset within row (16B granules)
  const unsigned short* ga[4];
  const unsigned short* gb[4];
  unsigned short* lad[4];
  unsigned short* lbd[4];
#pragma unroll
  for (int i = 0; i < 4; i++) {
    int seg = i * 4 + w;        // 0..15, wave-uniform
    int row = seg * 8 + srow;   // 0..127
    ga[i] = Ab + (long)row * lda + schunk;
    gb[i] = Bb + (long)row * ldb + schunk;
    lad[i] = &lA[seg * 512];
    lbd[i] = &lB[seg * 512];
  }
  // MFMA fragment LDS element offsets (row-major [128][64])
  int aoff[4], boff[4];
#pragma unroll
  for (int i = 0; i < 4; i++) {
    aoff[i] = (wm * 64 + i * 16 + (l & 15)) * BK + (l >> 4) * 8;
    boff[i] = (wn * 64 + i * 16 + (l & 15)) * BK + (l >> 4) * 8;
  }

  f32x4 acc[4][4] = {};
  for (int k0 = 0; k0 < Keff; k0 += BK) {
    __syncthreads();  // previous compute done before overwrite
#pragma unroll
    for (int i = 0; i < 4; i++) {
      gload_lds16(ga[i], lad[i]);
      gload_lds16(gb[i], lbd[i]);
    }
#pragma unroll
    for (int i = 0; i < 4; i++) { ga[i] += BK; gb[i] += BK; }
    __syncthreads();  // compiler drains vmcnt before barrier
#pragma unroll
    for (int kk = 0; kk < 2; kk++) {
      short8 af[4], bf[4];
#pragma unroll
      for (int i = 0; i < 4; i++) af[i] = *(const short8*)&lA[aoff[i] + kk * 32];
#pragma unroll
      for (int j = 0; j < 4; j++) bf[j] = *(const short8*)&lB[boff[j] + kk * 32];
#pragma unroll
      for (int i = 0; i < 4; i++)
#pragma unroll
        for (int j = 0; j < 4; j++)
          acc[i][j] = __builtin_amdgcn_mfma_f32_16x16x32_bf16(af[i], bf[j], acc[i][j], 0, 0, 0);
    }
  }

  // epilogue: D col = lane&15, row = (lane>>4)*4 + t   [m89-verified]
  int rh = l >> 4, cl = l & 15;
  long rowbase = (long)bm * BM + wm * 64 + rh * 4;
  int colbase = bn * BN + wn * 64 + cl;
#pragma unroll
  for (int j = 0; j < 4; j++) {
    int c = colbase + j * 16;
    float bv_ = BIAS ? bias[c] : 0.f;
#pragma unroll
    for (int i = 0; i < 4; i++) {
      long r0 = rowbase + i * 16;
      f32x4 v = acc[i][j];
      if constexpr (OUT_BF16) {
        unsigned short* Ch = (unsigned short*)C + (long)bz * sCz;
        if constexpr (STORE_TRANS) {
          ushort4 pk;
          pk.x = f2bu(v[0] * scale + bv_);
          pk.y = f2bu(v[1] * scale + bv_);
          pk.z = f2bu(v[2] * scale + bv_);
          pk.w = f2bu(v[3] * scale + bv_);
          *(ushort4*)(Ch + (long)c * ldc + r0) = pk;
        } else {
#pragma unroll
          for (int t = 0; t < 4; t++)
            Ch[(r0 + t) * (long)ldc + c] = f2bu(v[t] * scale + bv_);
        }
      } else {
        float* Cf = (float*)C + (long)bz * sCz;
#pragma unroll
        for (int t = 0; t < 4; t++)
          Cf[(r0 + t) * (long)ldc + c] = v[t] * scale + bv_;
      }
    }
  }
}

// ---------------- causal row softmax, fp32 scores -> bf16 P in place ----------------
// Row q reads fp32 scores[0..q], writes bf16 P at the row head (byte stride of rows
// stays 4*S). Zero-fills to the PV k-bound ((q/128+1)*128).
__global__ __launch_bounds__(256) void softmax_kernel(float* __restrict__ scores) {
  long r = blockIdx.x;
  int q = (int)(r & (S_ - 1));
  float* row = scores + r * (long)S_;
  int n = q + 1;
  int tid = threadIdx.x;

  float vv[8];
  float m = -1e30f;
  const float4* row4 = (const float4*)row;
#pragma unroll
  for (int i = 0; i < 2; i++) {
    int idx = tid + i * 256;
    float4 f = row4[idx];  // row fully allocated; mask below
    int kb = idx * 4;
    vv[i * 4 + 0] = (kb + 0 < n) ? f.x : -1e30f;
    vv[i * 4 + 1] = (kb + 1 < n) ? f.y : -1e30f;
    vv[i * 4 + 2] = (kb + 2 < n) ? f.z : -1e30f;
    vv[i * 4 + 3] = (kb + 3 < n) ? f.w : -1e30f;
  }
#pragma unroll
  for (int i = 0; i < 8; i++) m = fmaxf(m, vv[i]);
#pragma unroll
  for (int o = 32; o > 0; o >>= 1) m = fmaxf(m, __shfl_xor(m, o));
  __shared__ float red[8];
  int wv = tid >> 6, ln = tid & 63;
  if (ln == 0) red[wv] = m;
  __syncthreads();
  m = fmaxf(fmaxf(red[0], red[1]), fmaxf(red[2], red[3]));

  float s = 0.f;
#pragma unroll
  for (int i = 0; i < 8; i++) { vv[i] = __expf(vv[i] - m); s += vv[i]; }
#pragma unroll
  for (int o = 32; o > 0; o >>= 1) s += __shfl_xor(s, o);
  if (ln == 0) red[4 + wv] = s;
  __syncthreads();
  s = red[4] + red[5] + red[6] + red[7];
  float inv = 1.f / s;

  // all reads completed before the barriers above -> safe to overwrite in place
  unsigned short* prow = (unsigned short*)row;
  int nfill = ((q >> 7) + 1) << 7;
#pragma unroll
  for (int i = 0; i < 2; i++) {
    int kb = (tid + i * 256) * 4;
    if (kb < nfill) {
      ushort4 o;
      o.x = f2bu(vv[i * 4 + 0] * inv);
      o.y = f2bu(vv[i * 4 + 1] * inv);
      o.z = f2bu(vv[i * 4 + 2] * inv);
      o.w = f2bu(vv[i * 4 + 3] * inv);
      *(ushort4*)(prow + kb) = o;  // exp(-1e30)=0 covers k>q
    }
  }
}

// ---------------- host ----------------
extern "C" void kernel_launch(void* const* d_in, const int* in_sizes, int n_in,
                              void* d_out, int out_size, void* d_ws, size_t ws_size,
                              hipStream_t stream) {
  const float* x  = (const float*)d_in[0];
  // d_in[1] = mask (standard causal tril; handled structurally)
  const float* Wq = (const float*)d_in[2];
  const float* bq = (const float*)d_in[3];
  const float* Wk = (const float*)d_in[4];
  const float* bk = (const float*)d_in[5];
  const float* Wv = (const float*)d_in[6];
  const float* bv = (const float*)d_in[7];
  float* out = (float*)d_out;

  const long NX = (long)B_ * S_ * E_;  // 8388608
  const long NW = (long)E_ * E_;       // 1048576
  unsigned short* xb  = (unsigned short*)d_ws;
  unsigned short* wqb = xb + NX;
  unsigned short* wkb = wqb + NW;
  unsigned short* wvb = wkb + NW;
  unsigned short* Qb  = wvb + NW;
  unsigned short* Kb  = Qb + NX;
  unsigned short* Vtb = Kb + NX;            // layout [E][B*S]
  float* scores = (float*)(Vtb + NX);       // [B][S][S] fp32, P bf16 in place

  cvt_f32_bf16<<<8192, 256, 0, stream>>>(x, xb, (int)NX);
  cvt_f32_bf16<<<1024, 256, 0, stream>>>(Wq, wqb, (int)NW);
  cvt_f32_bf16<<<1024, 256, 0, stream>>>(Wk, wkb, (int)NW);
  cvt_f32_bf16<<<1024, 256, 0, stream>>>(Wv, wvb, (int)NW);

  // Q = x Wq^T + bq ; K = x Wk^T + bk   (bf16 out)
  gemm_bt<true, true, false, false, false><<<dim3(8, 64, 1), 256, 0, stream>>>(
      xb, 0, E_, wqb, 0, E_, bq, Qb, 0, E_, B_ * S_, E_, E_, 1.f);
  gemm_bt<true, true, false, false, false><<<dim3(8, 64, 1), 256, 0, stream>>>(
      xb, 0, E_, wkb, 0, E_, bk, Kb, 0, E_, B_ * S_, E_, E_, 1.f);
  // Vt[e][b*S+s] = (x Wv^T + bv)[b*S+s][e]  (transposed store)
  gemm_bt<true, true, false, false, true><<<dim3(8, 64, 1), 256, 0, stream>>>(
      xb, 0, E_, wvb, 0, E_, bv, Vtb, 0, B_ * S_, B_ * S_, E_, E_, 1.f);

  // scores = Q K^T / sqrt(E), lower-triangular tiles only, fp32
  gemm_bt<false, false, true, false, false><<<dim3(16, 16, 4), 256, 0, stream>>>(
      Qb, (long)S_ * E_, E_, Kb, (long)S_ * E_, E_, nullptr,
      scores, (long)S_ * S_, S_, S_, S_, E_, 0.03125f);

  softmax_kernel<<<B_ * S_, 256, 0, stream>>>(scores);

  // out = P V : A = P (bf16 rows at stride 2*S elements), B = Vt (N=E, K=S)
  gemm_bt<false, false, false, true, false><<<dim3(8, 16, 4), 256, 0, stream>>>(
      (const unsigned short*)scores, (long)S_ * S_ * 2, 2 * S_,
      Vtb, (long)S_, B_ * S_, nullptr,
      out, (long)S_ * E_, E_, S_, E_, S_, 1.f);
}